// Round 13
// baseline (98.509 us; speedup 1.0000x reference)
//
#include <hip/hip_runtime.h>
#include <hip/hip_bf16.h>

// CapsuleNet dynamic routing, fused per-sample. fp32 I/O:
// x: f32 [8192, 32, 8], W: f32 [32, 8, 256], out: f32 [8192, 16, 16].
// One block = 2 samples; thread t = (nc = t>>4, dc = t&15) owns column k = t.
// u_hat computed in f32 (dot2) then stored as PACKED f16 pairs (s0,s1) in
// v2h uhx[32] — xor-permuted order uhx[icb+j] = uh[icb+(j^dc)] (baked into
// the W-transpose gather), so the b_update butterfly is select-free AND each
// DPP exchange moves both samples in one 32-bit reg. c is stored f16
// interleaved c16h[n][ic][s] (2-byte writes, no RMW); c.uh = pk_fma_f16.
// b / softmax / squash stay f32. x staged to LDS; x reads = ds_read_b128.
// r12 fix: bit_cast cvt_pkrtz's __fp16-vector result to v2h.

#define S 2

typedef float    v2f __attribute__((ext_vector_type(2)));
typedef _Float16 v2h __attribute__((ext_vector_type(2)));

__device__ __forceinline__ v2h pack2h(float a, float b) {
  return __builtin_bit_cast(v2h, __builtin_amdgcn_cvt_pkrtz(a, b));  // v_cvt_pkrtz_f16_f32
}

// DPP cross-lane: value of `x` from lane (lane ^ k) within a 16-lane row.
// 0xB1 = quad_perm[1,0,3,2] (xor1)  0x4E = quad_perm[2,3,0,1] (xor2)
// 0x128 = row_ror:8 (xor8)  0x141 = row_half_mirror  0x140 = row_mirror
template <int CTRL>
__device__ __forceinline__ float dppf(float x) {
  return __builtin_bit_cast(float,
      __builtin_amdgcn_update_dpp(0, __builtin_bit_cast(int, x), CTRL, 0xF, 0xF, true));
}
template <int CTRL>
__device__ __forceinline__ v2h dpph(v2h v) {  // both samples in one DPP
  return __builtin_bit_cast(v2h,
      __builtin_amdgcn_update_dpp(0, __builtin_bit_cast(int, v), CTRL, 0xF, 0xF, true));
}
// Masked DPP keeping `old` on disabled banks (bound_ctrl=false: keep old).
template <int CTRL, int BANK>
__device__ __forceinline__ int dpp_old_i(int old, int x) {
  return __builtin_amdgcn_update_dpp(old, x, CTRL, 0xF, BANK, false);
}
// Transport s from lane^4 to every lane (validated r10):
// banks 0,2 (lanes 0-3,8-11): from lane+4 via row_shl:4 (0x104);
// banks 1,3 (lanes 4-7,12-15): from lane-4 via row_shr:4 (0x114).
__device__ __forceinline__ v2h xor4t_h(v2h s) {
  int si = __builtin_bit_cast(int, s);
  int ya = dpp_old_i<0x104, 0x5>(0, si);
  return __builtin_bit_cast(v2h, dpp_old_i<0x114, 0xA>(ya, si));
}

#if __has_builtin(__builtin_amdgcn_fdot2)
__device__ __forceinline__ float dot2(v2h a, v2h b, float c) {
  return __builtin_amdgcn_fdot2(a, b, c, false);  // v_dot2_f32_f16
}
#else
__device__ __forceinline__ float dot2(v2h a, v2h b, float c) {
  return fmaf((float)a.x, (float)b.x, fmaf((float)a.y, (float)b.y, c));
}
#endif

// Fused prep: blocks 0..255: W[ic][id][k](f32) -> Wth[ic_slot][k][id](f16)
// with the xor pre-permute (slot icb+j at column k holds row icb+(j^(k&15)));
// blocks 256..1279: x (f32) -> xh (f16), 8 elems/thread.
__global__ __launch_bounds__(256) void prep_kernel(const float* __restrict__ W,
                                                   const float* __restrict__ x,
                                                   _Float16* __restrict__ Wth,
                                                   _Float16* __restrict__ xh) {
  int bid = blockIdx.x;
  if (bid < 256) {
    int o       = bid * 256 + threadIdx.x;
    int ic_slot = o >> 11;
    int k       = (o >> 3) & 255;
    int id      = o & 7;
    int ic_src  = (ic_slot & 16) | ((ic_slot ^ k) & 15);
    Wth[o] = (_Float16)W[(ic_src * 8 + id) * 256 + k];
  } else {
    int tid = (bid - 256) * 256 + threadIdx.x;
    const float4* xp = (const float4*)x + tid * 2;
    float4 f0 = xp[0], f1 = xp[1];
    v2h h0 = {(_Float16)f0.x, (_Float16)f0.y};
    v2h h1 = {(_Float16)f0.z, (_Float16)f0.w};
    v2h h2 = {(_Float16)f1.x, (_Float16)f1.y};
    v2h h3 = {(_Float16)f1.z, (_Float16)f1.w};
    uint4 o;
    o.x = __builtin_bit_cast(unsigned, h0);
    o.y = __builtin_bit_cast(unsigned, h1);
    o.z = __builtin_bit_cast(unsigned, h2);
    o.w = __builtin_bit_cast(unsigned, h3);
    ((uint4*)xh)[tid] = o;
  }
}

// squash over the 16 dc lanes, both samples at once; DPP-only reduction (f32).
__device__ __forceinline__ v2f squash2(v2f o) {
  v2f s2 = o * o;
  s2.x += dppf<0xB1>(s2.x);   s2.y += dppf<0xB1>(s2.y);    // + lane^1
  s2.x += dppf<0x4E>(s2.x);   s2.y += dppf<0x4E>(s2.y);    // + lane^2
  s2.x += dppf<0x141>(s2.x);  s2.y += dppf<0x141>(s2.y);   // + lane^7
  s2.x += dppf<0x140>(s2.x);  s2.y += dppf<0x140>(s2.y);   // + lane^15
  s2 += (v2f){1e-7f, 1e-7f};
  v2f sc;
  sc.x = s2.x * __builtin_amdgcn_rsqf(s2.x) * __builtin_amdgcn_rcpf(1.f + s2.x);
  sc.y = s2.y * __builtin_amdgcn_rsqf(s2.y) * __builtin_amdgcn_rcpf(1.f + s2.y);
  return o * sc;  // sqrt(s2)/(1+s2) * o
}

// Select-free butterfly on xor-permuted packed-f16 uhx: one DPP moves both
// samples. Lane dc lands b[icb+dc] (f32) for both samples.
template <bool ASSIGN>
__device__ __forceinline__ void b_update2(v2h vh, const v2h* uhx, int dc,
                                          float* bp0, float* bp1) {
#pragma unroll
  for (int icb = 0; icb < 32; icb += 16) {
    v2h y[16];
#pragma unroll
    for (int j = 0; j < 16; ++j) y[j] = vh * uhx[icb + j];       // pk_mul_f16
#pragma unroll
    for (int j = 0; j < 8; ++j) y[j] += dpph<0x128>(y[j + 8]);   // + lane^8
#pragma unroll
    for (int j = 0; j < 4; ++j) y[j] += xor4t_h(y[j + 4]);       // + lane^4
#pragma unroll
    for (int j = 0; j < 2; ++j) y[j] += dpph<0x4E>(y[j + 2]);    // + lane^2
    y[0] += dpph<0xB1>(y[1]);                                    // + lane^1
    float e0 = (float)y[0].x, e1 = (float)y[0].y;
    if (ASSIGN) { bp0[icb + dc] = e0;  bp1[icb + dc] = e1; }
    else        { bp0[icb + dc] += e0; bp1[icb + dc] += e1; }
  }
}

__global__ __launch_bounds__(256, 4) void caps_kernel(const unsigned* __restrict__ xh32,
                                                      const uint4* __restrict__ Wt4,
                                                      float* __restrict__ out) {
  const int t  = threadIdx.x;
  const int nc = t >> 4;
  const int dc = t & 15;
  const int s0 = blockIdx.x * S;

  __shared__ float b_lds[S][16][33];       // +1 pad: nc-column reads conflict-free
  __shared__ _Float16 c16h[16][32][2];     // c[n][ic][s] f16; row = 128 B
  __shared__ __align__(16) _Float16 xh_lds[2 * 256];  // block's x, f16

  // ---- stage this block's x slice into LDS (coalesced dword copy) ----
  ((unsigned*)xh_lds)[t] = xh32[s0 * 128 + t];
  __syncthreads();

  v2h uhx[32];                 // packed (s0,s1); xor order: uhx[icb+j]=uh[icb+(j^dc)]
  v2f o2 = (v2f){0.f, 0.f};

  // ---- u_hat (f32 dot2 accum, packed to f16 once); round-0 sum fused ----
#pragma unroll
  for (int ic = 0; ic < 32; ++ic) {
    uint4 wv = Wt4[ic * 256 + t];  // 8 f16 weights, one coalesced dwordx4
    v2h w0 = __builtin_bit_cast(v2h, wv.x);
    v2h w1 = __builtin_bit_cast(v2h, wv.y);
    v2h w2 = __builtin_bit_cast(v2h, wv.z);
    v2h w3 = __builtin_bit_cast(v2h, wv.w);
    const int icx0 = (ic & 16) | ((ic ^ dc) & 15);  // source x row for this lane
    uint4 xv0 = *(const uint4*)(xh_lds + icx0 * 8);        // sample 0, 8 f16
    uint4 xv1 = *(const uint4*)(xh_lds + 256 + icx0 * 8);  // sample 1
    float a0 = dot2(__builtin_bit_cast(v2h, xv0.w), w3,
               dot2(__builtin_bit_cast(v2h, xv0.z), w2,
               dot2(__builtin_bit_cast(v2h, xv0.y), w1,
               dot2(__builtin_bit_cast(v2h, xv0.x), w0, 0.f))));
    float a1 = dot2(__builtin_bit_cast(v2h, xv1.w), w3,
               dot2(__builtin_bit_cast(v2h, xv1.z), w2,
               dot2(__builtin_bit_cast(v2h, xv1.y), w1,
               dot2(__builtin_bit_cast(v2h, xv1.x), w0, 0.f))));
    o2 += (v2f){a0, a1};
    uhx[ic] = pack2h(a0, a1);  // 1 inst pack to f16 pair
  }

  // ---- routing round 0: b = 0 => c = 1/16 ----
  {
    v2f v = squash2(o2 * (v2f){0.0625f, 0.0625f});
    v2h vh = pack2h(v.x, v.y);
    b_update2<true>(vh, uhx, dc, &b_lds[0][nc][0], &b_lds[1][nc][0]);
  }
  __syncthreads();

  // ---- rounds 1, 2 ----
#pragma unroll
  for (int r = 1; r < 3; ++r) {
    {  // distributed softmax over nc: all 256 threads. thread -> (s, ic, quarter)
      const int ss  = t >> 7;         // sample
      const int icc = (t >> 2) & 31;  // column
      const int q   = t & 3;          // rows 4q..4q+3
      // no max-subtraction: |b| bounded far below exp overflow; shift-invariant.
      float e0 = __expf(b_lds[ss][4 * q + 0][icc]);
      float e1 = __expf(b_lds[ss][4 * q + 1][icc]);
      float e2 = __expf(b_lds[ss][4 * q + 2][icc]);
      float e3 = __expf(b_lds[ss][4 * q + 3][icc]);
      float ps = (e0 + e1) + (e2 + e3);
      ps += dppf<0xB1>(ps);  // + lane^1 (quad)
      ps += dppf<0x4E>(ps);  // + lane^2 (quad) -> full 16-row sum
      float inv = __builtin_amdgcn_rcpf(ps);
      c16h[4 * q + 0][icc][ss] = (_Float16)(e0 * inv);  // b16 writes, no RMW
      c16h[4 * q + 1][icc][ss] = (_Float16)(e1 * inv);
      c16h[4 * q + 2][icc][ss] = (_Float16)(e2 * inv);
      c16h[4 * q + 3][icc][ss] = (_Float16)(e3 * inv);
    }
    __syncthreads();

    // c.uh on xor-permuted uhx, all pk_fma_f16: per j one xor-addr,
    // two b32 reads (icb=16 via +64B imm), two pk_fma.
    const v2h* crow = (const v2h*)&c16h[nc][0][0];
    v2h oh = (v2h){(_Float16)0.f, (_Float16)0.f};
#pragma unroll
    for (int j = 0; j < 16; ++j) {
      const int m = j ^ dc;
      v2h cA = crow[m];       // ic = m       (icb 0)
      v2h cB = crow[m + 16];  // ic = m + 16  (icb 16)
      oh = __builtin_elementwise_fma(cA, uhx[j], oh);
      oh = __builtin_elementwise_fma(cB, uhx[16 + j], oh);
    }
    v2f o = (v2f){(float)oh.x, (float)oh.y};
    v2f v = squash2(o);
    if (r == 2) {
      out[(s0 + 0) * 256 + t] = v.x;
      out[(s0 + 1) * 256 + t] = v.y;
    } else {
      v2h vh = pack2h(v.x, v.y);
      b_update2<false>(vh, uhx, dc, &b_lds[0][nc][0], &b_lds[1][nc][0]);
      __syncthreads();  // b complete before round-2 softmax; c overwrite safe
    }
  }
}

extern "C" void kernel_launch(void* const* d_in, const int* in_sizes, int n_in,
                              void* d_out, int out_size, void* d_ws, size_t ws_size,
                              hipStream_t stream) {
  const float* x = (const float*)d_in[0];
  const float* W = (const float*)d_in[1];
  _Float16* Wth = (_Float16*)d_ws;           // 128 KB: f16 W-transpose (xor order)
  _Float16* xh  = (_Float16*)d_ws + 65536;   // 4 MB: f16 x

  prep_kernel<<<1280, 256, 0, stream>>>(W, x, Wth, xh);
  caps_kernel<<<8192 / S, 256, 0, stream>>>((const unsigned*)xh, (const uint4*)Wth,
                                            (float*)d_out);
}

// Round 14
// 97.141 us; speedup vs baseline: 1.0141x; 1.0141x over previous
//
#include <hip/hip_runtime.h>
#include <hip/hip_bf16.h>

// CapsuleNet dynamic routing, fused per-sample. fp32 I/O:
// x: f32 [8192, 32, 8], W: f32 [32, 8, 256], out: f32 [8192, 16, 16].
// One block = 2 samples; thread t = (nc = t>>4, dc = t&15) owns column k = t.
// u_hat computed in f32 (dot2), stored packed f16 (s0,s1) in v2h uhx[32] —
// xor-permuted order uhx[icb+j] = uh[icb+(j^dc)] (baked into the W-transpose
// gather) -> select-free DPP butterfly, one DPP moves both samples.
// c stored f16 pairs, ROW STRIDE 40 v2h (160 B): read bank = (8*nc+m)%32 ->
// the wave's 4 nc-groups get bank offsets 0/8/16/24 -> 2-way = free
// (r13 had 128 B rows -> 4-way on all 64 c-reads -> 3.5M conflict cycles).
// x->f16 conversion folded into caps staging (no separate xh pass).

#define S 2

typedef float    v2f __attribute__((ext_vector_type(2)));
typedef _Float16 v2h __attribute__((ext_vector_type(2)));

__device__ __forceinline__ v2h pack2h(float a, float b) {
  return __builtin_bit_cast(v2h, __builtin_amdgcn_cvt_pkrtz(a, b));  // v_cvt_pkrtz_f16_f32
}

// DPP cross-lane: value of `x` from lane (lane ^ k) within a 16-lane row.
// 0xB1 = quad_perm[1,0,3,2] (xor1)  0x4E = quad_perm[2,3,0,1] (xor2)
// 0x128 = row_ror:8 (xor8)  0x141 = row_half_mirror  0x140 = row_mirror
template <int CTRL>
__device__ __forceinline__ float dppf(float x) {
  return __builtin_bit_cast(float,
      __builtin_amdgcn_update_dpp(0, __builtin_bit_cast(int, x), CTRL, 0xF, 0xF, true));
}
template <int CTRL>
__device__ __forceinline__ v2h dpph(v2h v) {  // both samples in one DPP
  return __builtin_bit_cast(v2h,
      __builtin_amdgcn_update_dpp(0, __builtin_bit_cast(int, v), CTRL, 0xF, 0xF, true));
}
// Masked DPP keeping `old` on disabled banks (bound_ctrl=false: keep old).
template <int CTRL, int BANK>
__device__ __forceinline__ int dpp_old_i(int old, int x) {
  return __builtin_amdgcn_update_dpp(old, x, CTRL, 0xF, BANK, false);
}
// Transport s from lane^4 to every lane (validated r10):
// banks 0,2 (lanes 0-3,8-11): from lane+4 via row_shl:4 (0x104);
// banks 1,3 (lanes 4-7,12-15): from lane-4 via row_shr:4 (0x114).
__device__ __forceinline__ v2h xor4t_h(v2h s) {
  int si = __builtin_bit_cast(int, s);
  int ya = dpp_old_i<0x104, 0x5>(0, si);
  return __builtin_bit_cast(v2h, dpp_old_i<0x114, 0xA>(ya, si));
}

#if __has_builtin(__builtin_amdgcn_fdot2)
__device__ __forceinline__ float dot2(v2h a, v2h b, float c) {
  return __builtin_amdgcn_fdot2(a, b, c, false);  // v_dot2_f32_f16
}
#else
__device__ __forceinline__ float dot2(v2h a, v2h b, float c) {
  return fmaf((float)a.x, (float)b.x, fmaf((float)a.y, (float)b.y, c));
}
#endif

// Prep (W only): W[ic][id][k](f32) -> Wth[ic_slot][k][id](f16) with the xor
// pre-permute: slot icb+j at column k holds row icb+(j^(k&15)).
__global__ __launch_bounds__(256) void prep_kernel(const float* __restrict__ W,
                                                   _Float16* __restrict__ Wth) {
  int o       = blockIdx.x * 256 + threadIdx.x;
  int ic_slot = o >> 11;
  int k       = (o >> 3) & 255;
  int id      = o & 7;
  int ic_src  = (ic_slot & 16) | ((ic_slot ^ k) & 15);
  Wth[o] = (_Float16)W[(ic_src * 8 + id) * 256 + k];
}

// squash over the 16 dc lanes, both samples at once; DPP-only reduction (f32).
__device__ __forceinline__ v2f squash2(v2f o) {
  v2f s2 = o * o;
  s2.x += dppf<0xB1>(s2.x);   s2.y += dppf<0xB1>(s2.y);    // + lane^1
  s2.x += dppf<0x4E>(s2.x);   s2.y += dppf<0x4E>(s2.y);    // + lane^2
  s2.x += dppf<0x141>(s2.x);  s2.y += dppf<0x141>(s2.y);   // + lane^7
  s2.x += dppf<0x140>(s2.x);  s2.y += dppf<0x140>(s2.y);   // + lane^15
  s2 += (v2f){1e-7f, 1e-7f};
  v2f sc;
  sc.x = s2.x * __builtin_amdgcn_rsqf(s2.x) * __builtin_amdgcn_rcpf(1.f + s2.x);
  sc.y = s2.y * __builtin_amdgcn_rsqf(s2.y) * __builtin_amdgcn_rcpf(1.f + s2.y);
  return o * sc;  // sqrt(s2)/(1+s2) * o
}

// Select-free butterfly on xor-permuted packed-f16 uhx: one DPP moves both
// samples. Lane dc lands b[icb+dc] (f32) for both samples.
template <bool ASSIGN>
__device__ __forceinline__ void b_update2(v2h vh, const v2h* uhx, int dc,
                                          float* bp0, float* bp1) {
#pragma unroll
  for (int icb = 0; icb < 32; icb += 16) {
    v2h y[16];
#pragma unroll
    for (int j = 0; j < 16; ++j) y[j] = vh * uhx[icb + j];       // pk_mul_f16
#pragma unroll
    for (int j = 0; j < 8; ++j) y[j] += dpph<0x128>(y[j + 8]);   // + lane^8
#pragma unroll
    for (int j = 0; j < 4; ++j) y[j] += xor4t_h(y[j + 4]);       // + lane^4
#pragma unroll
    for (int j = 0; j < 2; ++j) y[j] += dpph<0x4E>(y[j + 2]);    // + lane^2
    y[0] += dpph<0xB1>(y[1]);                                    // + lane^1
    float e0 = (float)y[0].x, e1 = (float)y[0].y;
    if (ASSIGN) { bp0[icb + dc] = e0;  bp1[icb + dc] = e1; }
    else        { bp0[icb + dc] += e0; bp1[icb + dc] += e1; }
  }
}

#define CSTRIDE 40  // v2h per c-row: read bank = (8*nc+m)%32 -> 2-way (free)

__global__ __launch_bounds__(256, 4) void caps_kernel(const float* __restrict__ x,
                                                      const uint4* __restrict__ Wt4,
                                                      float* __restrict__ out) {
  const int t  = threadIdx.x;
  const int nc = t >> 4;
  const int dc = t & 15;
  const int s0 = blockIdx.x * S;

  __shared__ float b_lds[S][16][33];        // +1 pad: nc-column reads conflict-free
  __shared__ v2h c16h[16 * CSTRIDE];        // c[n][ic][s] f16 pairs, stride-40 rows
  __shared__ __align__(16) _Float16 xh_lds[2 * 256];  // block's x, f16

  // ---- stage x: 2 f32/thread from global, convert, 1 dword to LDS ----
  {
    const float2* xs = (const float2*)(x + s0 * 256);
    float2 xv = xs[t];
    ((unsigned*)xh_lds)[t] = __builtin_bit_cast(unsigned, pack2h(xv.x, xv.y));
  }
  __syncthreads();

  v2h uhx[32];                 // packed (s0,s1); xor order: uhx[icb+j]=uh[icb+(j^dc)]
  v2f o2 = (v2f){0.f, 0.f};

  // ---- u_hat (f32 dot2 accum, packed to f16 once); round-0 sum fused ----
#pragma unroll
  for (int ic = 0; ic < 32; ++ic) {
    uint4 wv = Wt4[ic * 256 + t];  // 8 f16 weights, one coalesced dwordx4
    v2h w0 = __builtin_bit_cast(v2h, wv.x);
    v2h w1 = __builtin_bit_cast(v2h, wv.y);
    v2h w2 = __builtin_bit_cast(v2h, wv.z);
    v2h w3 = __builtin_bit_cast(v2h, wv.w);
    const int icx0 = (ic & 16) | ((ic ^ dc) & 15);  // source x row for this lane
    uint4 xv0 = *(const uint4*)(xh_lds + icx0 * 8);        // sample 0, 8 f16
    uint4 xv1 = *(const uint4*)(xh_lds + 256 + icx0 * 8);  // sample 1
    float a0 = dot2(__builtin_bit_cast(v2h, xv0.w), w3,
               dot2(__builtin_bit_cast(v2h, xv0.z), w2,
               dot2(__builtin_bit_cast(v2h, xv0.y), w1,
               dot2(__builtin_bit_cast(v2h, xv0.x), w0, 0.f))));
    float a1 = dot2(__builtin_bit_cast(v2h, xv1.w), w3,
               dot2(__builtin_bit_cast(v2h, xv1.z), w2,
               dot2(__builtin_bit_cast(v2h, xv1.y), w1,
               dot2(__builtin_bit_cast(v2h, xv1.x), w0, 0.f))));
    o2 += (v2f){a0, a1};
    uhx[ic] = pack2h(a0, a1);  // 1 inst pack to f16 pair
  }

  // ---- routing round 0: b = 0 => c = 1/16 ----
  {
    v2f v = squash2(o2 * (v2f){0.0625f, 0.0625f});
    v2h vh = pack2h(v.x, v.y);
    b_update2<true>(vh, uhx, dc, &b_lds[0][nc][0], &b_lds[1][nc][0]);
  }
  __syncthreads();

  // ---- rounds 1, 2 ----
#pragma unroll
  for (int r = 1; r < 3; ++r) {
    {  // distributed softmax over nc: all 256 threads. thread -> (s, ic, quarter)
      const int ss  = t >> 7;         // sample
      const int icc = (t >> 2) & 31;  // column
      const int q   = t & 3;          // rows 4q..4q+3
      // no max-subtraction: |b| bounded far below exp overflow; shift-invariant.
      float e0 = __expf(b_lds[ss][4 * q + 0][icc]);
      float e1 = __expf(b_lds[ss][4 * q + 1][icc]);
      float e2 = __expf(b_lds[ss][4 * q + 2][icc]);
      float e3 = __expf(b_lds[ss][4 * q + 3][icc]);
      float ps = (e0 + e1) + (e2 + e3);
      ps += dppf<0xB1>(ps);  // + lane^1 (quad)
      ps += dppf<0x4E>(ps);  // + lane^2 (quad) -> full 16-row sum
      float inv = __builtin_amdgcn_rcpf(ps);
      _Float16* cw = (_Float16*)c16h + ss;  // component ss of each pair
      cw[((4 * q + 0) * CSTRIDE + icc) * 2] = (_Float16)(e0 * inv);
      cw[((4 * q + 1) * CSTRIDE + icc) * 2] = (_Float16)(e1 * inv);
      cw[((4 * q + 2) * CSTRIDE + icc) * 2] = (_Float16)(e2 * inv);
      cw[((4 * q + 3) * CSTRIDE + icc) * 2] = (_Float16)(e3 * inv);
    }
    __syncthreads();

    // c.uh on xor-permuted uhx, all pk_fma_f16: per j one xor-addr,
    // two b32 reads (icb=16 via imm offset), two pk_fma.
    const v2h* crow = &c16h[nc * CSTRIDE];
    v2h oh = (v2h){(_Float16)0.f, (_Float16)0.f};
#pragma unroll
    for (int j = 0; j < 16; ++j) {
      const int m = j ^ dc;
      v2h cA = crow[m];       // ic = m       (icb 0)
      v2h cB = crow[m + 16];  // ic = m + 16  (icb 16)
      oh = __builtin_elementwise_fma(cA, uhx[j], oh);
      oh = __builtin_elementwise_fma(cB, uhx[16 + j], oh);
    }
    v2f o = (v2f){(float)oh.x, (float)oh.y};
    v2f v = squash2(o);
    if (r == 2) {
      out[(s0 + 0) * 256 + t] = v.x;
      out[(s0 + 1) * 256 + t] = v.y;
    } else {
      v2h vh = pack2h(v.x, v.y);
      b_update2<false>(vh, uhx, dc, &b_lds[0][nc][0], &b_lds[1][nc][0]);
      __syncthreads();  // b complete before round-2 softmax; c overwrite safe
    }
  }
}

extern "C" void kernel_launch(void* const* d_in, const int* in_sizes, int n_in,
                              void* d_out, int out_size, void* d_ws, size_t ws_size,
                              hipStream_t stream) {
  const float* x = (const float*)d_in[0];
  const float* W = (const float*)d_in[1];
  _Float16* Wth = (_Float16*)d_ws;  // 128 KB: f16 W-transpose (xor order)

  prep_kernel<<<256, 256, 0, stream>>>(W, Wth);
  caps_kernel<<<8192 / S, 256, 0, stream>>>(x, (const uint4*)Wth, (float*)d_out);
}

// Round 15
// 91.303 us; speedup vs baseline: 1.0789x; 1.0639x over previous
//
#include <hip/hip_runtime.h>
#include <hip/hip_bf16.h>

// CapsuleNet dynamic routing, fused per-sample. fp32 I/O:
// x: f32 [8192, 32, 8], W: f32 [32, 8, 256], out: f32 [8192, 16, 16].
// One block = 2 samples; thread t = (nc = t>>4, dc = t&15) owns column k = t.
// r15: x reads are WAVE-UNIFORM s_loads of pre-converted f16 (zero VALU/DS
// cost) — the r10-r14 LDS x-gather saturated the DS pipe (3.5M conflict
// cycles, ~76% DS busy). uh stored NORMAL-order packed f16 (s0,s1) v2h[32];
// butterfly uses 32-bit cndmask selects (both samples per select) + DPP
// transports. c in f16 pairs stride-40 rows; c.uh reads are compile-time
// offsets -> 4 distinct broadcast addresses/wave at banks 0/8/16/24+j.
// Occupancy raised: __launch_bounds__(256,6) (VGPR=44 measured, 85 budget).

#define S 2

typedef float    v2f __attribute__((ext_vector_type(2)));
typedef _Float16 v2h __attribute__((ext_vector_type(2)));

__device__ __forceinline__ v2h pack2h(float a, float b) {
  return __builtin_bit_cast(v2h, __builtin_amdgcn_cvt_pkrtz(a, b));  // v_cvt_pkrtz_f16_f32
}

// DPP cross-lane: value of `x` from lane (lane ^ k) within a 16-lane row.
// 0xB1 = quad_perm[1,0,3,2] (xor1)  0x4E = quad_perm[2,3,0,1] (xor2)
// 0x128 = row_ror:8 (xor8)  0x141 = row_half_mirror  0x140 = row_mirror
template <int CTRL>
__device__ __forceinline__ float dppf(float x) {
  return __builtin_bit_cast(float,
      __builtin_amdgcn_update_dpp(0, __builtin_bit_cast(int, x), CTRL, 0xF, 0xF, true));
}
template <int CTRL>
__device__ __forceinline__ v2h dpph(v2h v) {  // both samples in one DPP
  return __builtin_bit_cast(v2h,
      __builtin_amdgcn_update_dpp(0, __builtin_bit_cast(int, v), CTRL, 0xF, 0xF, true));
}
// Masked DPP keeping `old` on disabled banks (bound_ctrl=false: keep old).
template <int CTRL, int BANK>
__device__ __forceinline__ int dpp_old_i(int old, int x) {
  return __builtin_amdgcn_update_dpp(old, x, CTRL, 0xF, BANK, false);
}
// Deliver partner(lane^4)'s value of s to every lane (validated r10/r13):
// banks 0,2 (lanes 0-3,8-11): from lane+4 via row_shl:4 (0x104);
// banks 1,3 (lanes 4-7,12-15): from lane-4 via row_shr:4 (0x114).
__device__ __forceinline__ v2h xor4t_h(v2h s) {
  int si = __builtin_bit_cast(int, s);
  int ya = dpp_old_i<0x104, 0x5>(0, si);
  return __builtin_bit_cast(v2h, dpp_old_i<0x114, 0xA>(ya, si));
}

#if __has_builtin(__builtin_amdgcn_fdot2)
__device__ __forceinline__ float dot2(v2h a, v2h b, float c) {
  return __builtin_amdgcn_fdot2(a, b, c, false);  // v_dot2_f32_f16
}
#else
__device__ __forceinline__ float dot2(v2h a, v2h b, float c) {
  return fmaf((float)a.x, (float)b.x, fmaf((float)a.y, (float)b.y, c));
}
#endif

// Fused prep: blocks 0..255: W[ic][id][k](f32) -> Wth[ic][k][id](f16), NO
// permute; blocks 256..1279: x (f32) -> xh (f16), 8 elems/thread.
__global__ __launch_bounds__(256) void prep_kernel(const float* __restrict__ W,
                                                   const float* __restrict__ x,
                                                   _Float16* __restrict__ Wth,
                                                   _Float16* __restrict__ xh) {
  int bid = blockIdx.x;
  if (bid < 256) {
    int o  = bid * 256 + threadIdx.x;
    int ic = o >> 11;
    int k  = (o >> 3) & 255;
    int id = o & 7;
    Wth[o] = (_Float16)W[(ic * 8 + id) * 256 + k];
  } else {
    int tid = (bid - 256) * 256 + threadIdx.x;
    const float4* xp = (const float4*)x + tid * 2;
    float4 f0 = xp[0], f1 = xp[1];
    v2h h0 = {(_Float16)f0.x, (_Float16)f0.y};
    v2h h1 = {(_Float16)f0.z, (_Float16)f0.w};
    v2h h2 = {(_Float16)f1.x, (_Float16)f1.y};
    v2h h3 = {(_Float16)f1.z, (_Float16)f1.w};
    uint4 o;
    o.x = __builtin_bit_cast(unsigned, h0);
    o.y = __builtin_bit_cast(unsigned, h1);
    o.z = __builtin_bit_cast(unsigned, h2);
    o.w = __builtin_bit_cast(unsigned, h3);
    ((uint4*)xh)[tid] = o;
  }
}

// squash over the 16 dc lanes, both samples at once; DPP-only reduction (f32).
__device__ __forceinline__ v2f squash2(v2f o) {
  v2f s2 = o * o;
  s2.x += dppf<0xB1>(s2.x);   s2.y += dppf<0xB1>(s2.y);    // + lane^1
  s2.x += dppf<0x4E>(s2.x);   s2.y += dppf<0x4E>(s2.y);    // + lane^2
  s2.x += dppf<0x141>(s2.x);  s2.y += dppf<0x141>(s2.y);   // + lane^7
  s2.x += dppf<0x140>(s2.x);  s2.y += dppf<0x140>(s2.y);   // + lane^15
  s2 += (v2f){1e-7f, 1e-7f};
  v2f sc;
  sc.x = s2.x * __builtin_amdgcn_rsqf(s2.x) * __builtin_amdgcn_rcpf(1.f + s2.x);
  sc.y = s2.y * __builtin_amdgcn_rsqf(s2.y) * __builtin_amdgcn_rcpf(1.f + s2.y);
  return o * sc;  // sqrt(s2)/(1+s2) * o
}

// Butterfly transpose-reduction on NORMAL-order packed-f16 uh (selects are
// single 32-bit cndmasks moving both samples). Lane dc lands b[icb+dc] (f32).
// Levels 8/2/1 via DPP xor; level 4 via the masked dual-DPP transport.
template <bool ASSIGN>
__device__ __forceinline__ void b_update2(v2h vh, const v2h* uh, int dc,
                                          float* bp0, float* bp1) {
#pragma unroll
  for (int icb = 0; icb < 32; icb += 16) {
    v2h a[16];
#pragma unroll
    for (int j = 0; j < 16; ++j) a[j] = vh * uh[icb + j];  // pk_mul_f16
    v2h b8[8];
    const bool u8 = (dc & 8) != 0;
#pragma unroll
    for (int j = 0; j < 8; ++j) {
      v2h send = u8 ? a[j] : a[j + 8];
      v2h recv = dpph<0x128>(send);              // partner(lane^8)'s send
      b8[j] = (u8 ? a[j + 8] : a[j]) + recv;
    }
    v2h c4[4];
    const bool u4 = (dc & 4) != 0;
#pragma unroll
    for (int j = 0; j < 4; ++j) {
      v2h send = u4 ? b8[j] : b8[j + 4];
      v2h recv = xor4t_h(send);                  // partner(lane^4)'s send
      c4[j] = (u4 ? b8[j + 4] : b8[j]) + recv;
    }
    v2h d2[2];
    const bool u2 = (dc & 2) != 0;
#pragma unroll
    for (int j = 0; j < 2; ++j) {
      v2h send = u2 ? c4[j] : c4[j + 2];
      v2h recv = dpph<0x4E>(send);               // partner(lane^2)'s send
      d2[j] = (u2 ? c4[j + 2] : c4[j]) + recv;
    }
    const bool u1 = (dc & 1) != 0;
    v2h send = u1 ? d2[0] : d2[1];
    v2h recv = dpph<0xB1>(send);                 // partner(lane^1)'s send
    v2h e = (u1 ? d2[1] : d2[0]) + recv;
    float e0 = (float)e.x, e1 = (float)e.y;
    if (ASSIGN) { bp0[icb + dc] = e0;  bp1[icb + dc] = e1; }
    else        { bp0[icb + dc] += e0; bp1[icb + dc] += e1; }
  }
}

#define CSTRIDE 40  // v2h per c-row: banks (8*nc+j)%32 -> 4 distinct broadcast addrs

__global__ __launch_bounds__(256, 6) void caps_kernel(const _Float16* __restrict__ xh,
                                                      const uint4* __restrict__ Wt4,
                                                      float* __restrict__ out) {
  const int t  = threadIdx.x;
  const int nc = t >> 4;
  const int dc = t & 15;
  const int s0 = blockIdx.x * S;

  __shared__ float b_lds[S][16][33];   // +1 pad: nc-column reads conflict-free
  __shared__ v2h c16h[16 * CSTRIDE];   // c[n][ic] f16 pairs, stride-40 rows

  v2h uh[32];                          // packed (s0,s1), normal order
  v2f o2 = (v2f){0.f, 0.f};

  // ---- u_hat: wave-uniform x (s_load, free) + one b128 W load per ic ----
  const v2h* xp0 = (const v2h*)(xh + (s0 + 0) * 256);  // block-uniform -> s_load
  const v2h* xp1 = (const v2h*)(xh + (s0 + 1) * 256);
#pragma unroll
  for (int ic = 0; ic < 32; ++ic) {
    uint4 wv = Wt4[ic * 256 + t];  // 8 f16 weights, one coalesced dwordx4
    v2h w0 = __builtin_bit_cast(v2h, wv.x);
    v2h w1 = __builtin_bit_cast(v2h, wv.y);
    v2h w2 = __builtin_bit_cast(v2h, wv.z);
    v2h w3 = __builtin_bit_cast(v2h, wv.w);
    float a0 = dot2(xp0[ic * 4 + 3], w3,
               dot2(xp0[ic * 4 + 2], w2,
               dot2(xp0[ic * 4 + 1], w1,
               dot2(xp0[ic * 4 + 0], w0, 0.f))));
    float a1 = dot2(xp1[ic * 4 + 3], w3,
               dot2(xp1[ic * 4 + 2], w2,
               dot2(xp1[ic * 4 + 1], w1,
               dot2(xp1[ic * 4 + 0], w0, 0.f))));
    o2 += (v2f){a0, a1};
    uh[ic] = pack2h(a0, a1);  // 1 inst pack to f16 pair
  }

  // ---- routing round 0: b = 0 => c = 1/16 ----
  {
    v2f v = squash2(o2 * (v2f){0.0625f, 0.0625f});
    v2h vh = pack2h(v.x, v.y);
    b_update2<true>(vh, uh, dc, &b_lds[0][nc][0], &b_lds[1][nc][0]);
  }
  __syncthreads();

  // ---- rounds 1, 2 ----
#pragma unroll
  for (int r = 1; r < 3; ++r) {
    {  // distributed softmax over nc: all 256 threads. thread -> (s, ic, quarter)
      const int ss  = t >> 7;         // sample
      const int icc = (t >> 2) & 31;  // column
      const int q   = t & 3;          // rows 4q..4q+3
      // no max-subtraction: |b| bounded far below exp overflow; shift-invariant.
      float e0 = __expf(b_lds[ss][4 * q + 0][icc]);
      float e1 = __expf(b_lds[ss][4 * q + 1][icc]);
      float e2 = __expf(b_lds[ss][4 * q + 2][icc]);
      float e3 = __expf(b_lds[ss][4 * q + 3][icc]);
      float ps = (e0 + e1) + (e2 + e3);
      ps += dppf<0xB1>(ps);  // + lane^1 (quad)
      ps += dppf<0x4E>(ps);  // + lane^2 (quad) -> full 16-row sum
      float inv = __builtin_amdgcn_rcpf(ps);
      _Float16* cw = (_Float16*)c16h + ss;  // component ss of each pair
      cw[((4 * q + 0) * CSTRIDE + icc) * 2] = (_Float16)(e0 * inv);
      cw[((4 * q + 1) * CSTRIDE + icc) * 2] = (_Float16)(e1 * inv);
      cw[((4 * q + 2) * CSTRIDE + icc) * 2] = (_Float16)(e2 * inv);
      cw[((4 * q + 3) * CSTRIDE + icc) * 2] = (_Float16)(e3 * inv);
    }
    __syncthreads();

    // c.uh, normal order: compile-time offsets; per wave-issue only 4
    // distinct broadcast addresses (one per nc) at banks (8*nc+j)%32.
    const v2h* crow = &c16h[nc * CSTRIDE];
    v2h oh = (v2h){(_Float16)0.f, (_Float16)0.f};
#pragma unroll
    for (int j = 0; j < 16; ++j) {
      v2h cA = crow[j];       // ic = j       (icb 0)
      v2h cB = crow[j + 16];  // ic = j + 16  (icb 16)
      oh = __builtin_elementwise_fma(cA, uh[j], oh);
      oh = __builtin_elementwise_fma(cB, uh[16 + j], oh);
    }
    v2f o = (v2f){(float)oh.x, (float)oh.y};
    v2f v = squash2(o);
    if (r == 2) {
      out[(s0 + 0) * 256 + t] = v.x;
      out[(s0 + 1) * 256 + t] = v.y;
    } else {
      v2h vh = pack2h(v.x, v.y);
      b_update2<false>(vh, uh, dc, &b_lds[0][nc][0], &b_lds[1][nc][0]);
      __syncthreads();  // b complete before round-2 softmax; c overwrite safe
    }
  }
}

extern "C" void kernel_launch(void* const* d_in, const int* in_sizes, int n_in,
                              void* d_out, int out_size, void* d_ws, size_t ws_size,
                              hipStream_t stream) {
  const float* x = (const float*)d_in[0];
  const float* W = (const float*)d_in[1];
  _Float16* Wth = (_Float16*)d_ws;           // 128 KB: f16 W-transpose
  _Float16* xh  = (_Float16*)d_ws + 65536;   // 4 MB: f16 x

  prep_kernel<<<1280, 256, 0, stream>>>(W, x, Wth, xh);
  caps_kernel<<<8192 / S, 256, 0, stream>>>(xh, (const uint4*)Wth, (float*)d_out);
}